// Round 1
// baseline (73.838 us; speedup 1.0000x reference)
//
#include <hip/hip_runtime.h>
#include <hip/hip_bf16.h>
#include <stdint.h>

#define G1CAST(p) ((const __attribute__((address_space(1))) void*)(p))
#define L3CAST(p) ((__attribute__((address_space(3))) void*)(p))

typedef short bf16x8 __attribute__((ext_vector_type(8)));
typedef float f32x4 __attribute__((ext_vector_type(4)));

__device__ __forceinline__ short f2bf(float f) {
    __hip_bfloat16 b = __float2bfloat16(f);
    return __builtin_bit_cast(short, b);
}

// ---------------------------------------------------------------------------
// Kernel 1: relayout+convert weights to bf16.
// W_cat[n][gate][j][kk], kk in [0,1024): kk<512 -> W_ih[n][gate*512+j][kk]
//                                        kk>=512 -> W_hh[n][gate*512+j][kk-512]
// ---------------------------------------------------------------------------
__global__ __launch_bounds__(256) void wconv_kernel(const float* __restrict__ Wih,
                                                    const float* __restrict__ Whh,
                                                    short* __restrict__ Wcat) {
    const int tid = blockIdx.x * 256 + threadIdx.x;   // 1,572,864 threads
    const int64_t e = (int64_t)tid * 8;               // 8 elems / thread
    const int kk = (int)(e & 1023);
    const int row = (int)(e >> 10);                   // n*1536 + (gate*512+j)
    const int n = row / 1536;
    const int gr = row - n * 1536;
    const float* src = (kk < 512)
        ? Wih + ((int64_t)n * 786432 + (int64_t)gr * 512 + kk)
        : Whh + ((int64_t)n * 786432 + (int64_t)gr * 512 + (kk - 512));
    const float4 a = ((const float4*)src)[0];
    const float4 b = ((const float4*)src)[1];
    bf16x8 o;
    o[0] = f2bf(a.x); o[1] = f2bf(a.y); o[2] = f2bf(a.z); o[3] = f2bf(a.w);
    o[4] = f2bf(b.x); o[5] = f2bf(b.y); o[6] = f2bf(b.z); o[7] = f2bf(b.w);
    *(bf16x8*)(Wcat + e) = o;
}

// ---------------------------------------------------------------------------
// Kernel 2: fused block-diagonal GRU.
// Per block n: s_r/s_z accumulate over concat K=1024; i_n over kk<512,
// h_n over kk>=512. Tile: BM=128 (batch) x BN=64 (j), BK=64, 8 waves.
// ---------------------------------------------------------------------------
#define BM 128
#define BN 64
#define KSTEPS 16

__global__ __launch_bounds__(512, 2) void gru_kernel(
    const float* __restrict__ x, const float* __restrict__ hst,
    const short* __restrict__ Wcat,
    const float* __restrict__ b_ih, const float* __restrict__ b_hh,
    float* __restrict__ out)
{
    __shared__ short ldsA[2][BM * 64];        // 2 x 16 KB, [row][kk] swizzled
    __shared__ short ldsB[2][3 * BN * 64];    // 2 x 24 KB, [gate][row][kk] swizzled

    const int tid = threadIdx.x;
    const int wg = blockIdx.x;
    const int bt = wg >> 6;                   // batch tile 0..7
    const int jt = wg & 63;                   // 0..63
    const int nblk = jt >> 3;                 // block 0..7
    const int j0b = (jt & 7) * BN;            // j offset within block
    const int brow0 = bt * BM;

    const int lane = tid & 63;
    const int wave = tid >> 6;
    const int wm = wave >> 1;                 // 0..3 -> 32-row slice
    const int wn = wave & 1;                  // 0..1 -> 32-col slice
    const int l15 = lane & 15;
    const int l4 = lane >> 4;

    // A staging map: thread -> (row, 16-float segment)
    const int arow = tid >> 2;                // 0..127
    const int aseg = tid & 3;                 // 0..3
    const size_t a_off = (size_t)(brow0 + arow) * 4096 + (size_t)nblk * 512 + aseg * 16;
    const int aswz = (arow & 7) << 4;
    const int a_ds0 = arow * 128 + ((aseg * 32) ^ aswz);
    const int a_ds1 = arow * 128 + ((aseg * 32 + 16) ^ aswz);

    // B staging map (global_load_lds, pre-swizzled source)
    const int btrow = tid >> 3;               // 0..63
    const int bcb_sw = ((tid & 7) * 16) ^ ((btrow & 7) << 4);
    const size_t w_off = ((size_t)nblk * 1536 + (size_t)(j0b + btrow)) * 1024 + (bcb_sw >> 1);

    f32x4 acc_r[2][2] = {};
    f32x4 acc_z[2][2] = {};
    f32x4 acc_nx[2][2] = {};
    f32x4 acc_nh[2][2] = {};

    auto stageB = [&](int buf, int ks) {
        const short* wsrc = Wcat + w_off + ks * 64;
        char* dstbase = (char*)&ldsB[buf][0] + tid * 16;
        #pragma unroll
        for (int g = 0; g < 3; ++g) {
            __builtin_amdgcn_global_load_lds(G1CAST(wsrc + (size_t)g * 524288),
                                             L3CAST(dstbase + g * 8192), 16, 0, 0);
        }
    };

    auto cvtWriteA = [&](int buf, const float4& av0, const float4& av1,
                         const float4& av2, const float4& av3) {
        bf16x8 w0, w1;
        w0[0] = f2bf(av0.x); w0[1] = f2bf(av0.y); w0[2] = f2bf(av0.z); w0[3] = f2bf(av0.w);
        w0[4] = f2bf(av1.x); w0[5] = f2bf(av1.y); w0[6] = f2bf(av1.z); w0[7] = f2bf(av1.w);
        w1[0] = f2bf(av2.x); w1[1] = f2bf(av2.y); w1[2] = f2bf(av2.z); w1[3] = f2bf(av2.w);
        w1[4] = f2bf(av3.x); w1[5] = f2bf(av3.y); w1[6] = f2bf(av3.z); w1[7] = f2bf(av3.w);
        char* Aw = (char*)&ldsA[buf][0];
        *(bf16x8*)(Aw + a_ds0) = w0;
        *(bf16x8*)(Aw + a_ds1) = w1;
    };

    auto computeStep = [&](int buf, f32x4 (&accN)[2][2]) {
        const char* Ab = (const char*)&ldsA[buf][0];
        const char* Bb = (const char*)&ldsB[buf][0];
        bf16x8 af[2][2];
        #pragma unroll
        for (int m = 0; m < 2; ++m) {
            const int row = wm * 32 + m * 16 + l15;
            const int sw = (row & 7) << 4;
            #pragma unroll
            for (int kc = 0; kc < 2; ++kc)
                af[m][kc] = *(const bf16x8*)(Ab + row * 128 + ((kc * 64 + l4 * 16) ^ sw));
        }
        auto doGate = [&](int g, f32x4 (&acc)[2][2]) {
            bf16x8 bfv[2][2];
            #pragma unroll
            for (int nf = 0; nf < 2; ++nf) {
                const int row = wn * 32 + nf * 16 + l15;
                const int sw = (row & 7) << 4;
                #pragma unroll
                for (int kc = 0; kc < 2; ++kc)
                    bfv[nf][kc] = *(const bf16x8*)(Bb + g * 8192 + row * 128 + ((kc * 64 + l4 * 16) ^ sw));
            }
            #pragma unroll
            for (int m = 0; m < 2; ++m)
                #pragma unroll
                for (int nf = 0; nf < 2; ++nf)
                    #pragma unroll
                    for (int kc = 0; kc < 2; ++kc)
                        acc[m][nf] = __builtin_amdgcn_mfma_f32_16x16x32_bf16(
                            af[m][kc], bfv[nf][kc], acc[m][nf], 0, 0, 0);
        };
        doGate(0, acc_r);
        doGate(1, acc_z);
        doGate(2, accN);
    };

    auto kbody = [&](int ks, f32x4 (&accN)[2][2]) {
        const int cur = ks & 1;
        const int nxt = cur ^ 1;
        const bool hn = (ks + 1 < KSTEPS);
        float4 av0, av1, av2, av3;
        if (hn) {
            stageB(nxt, ks + 1);   // async: in flight across compute
            const float* asrc = (ks + 1 < 8) ? x : hst;
            const float4* ap = (const float4*)(asrc + a_off + (size_t)((ks + 1) & 7) * 64);
            av0 = ap[0]; av1 = ap[1]; av2 = ap[2]; av3 = ap[3];
        }
        computeStep(cur, accN);
        if (hn) cvtWriteA(nxt, av0, av1, av2, av3);
        __syncthreads();           // drains vmcnt (B tiles) + lgkm (A writes)
    };

    // prologue: stage ks=0 into buf 0
    {
        stageB(0, 0);
        const float4* ap = (const float4*)(x + a_off);
        float4 av0 = ap[0], av1 = ap[1], av2 = ap[2], av3 = ap[3];
        cvtWriteA(0, av0, av1, av2, av3);
        __syncthreads();
    }
    for (int ks = 0; ks < 8; ++ks) kbody(ks, acc_nx);
    for (int ks = 8; ks < KSTEPS; ++ks) kbody(ks, acc_nh);

    // ---- epilogue: gates + output ----
    #pragma unroll
    for (int nf = 0; nf < 2; ++nf) {
        const int jb = j0b + wn * 32 + nf * 16 + l15;     // [0,512)
        const int bb = nblk * 1536 + jb;
        const float br = b_ih[bb] + b_hh[bb];
        const float bz = b_ih[bb + 512] + b_hh[bb + 512];
        const float bnx = b_ih[bb + 1024];
        const float bnh = b_hh[bb + 1024];
        const int gcol = nblk * 512 + jb;
        #pragma unroll
        for (int m = 0; m < 2; ++m) {
            const int rowb = brow0 + wm * 32 + m * 16 + l4 * 4;
            #pragma unroll
            for (int r = 0; r < 4; ++r) {
                const size_t idx = (size_t)(rowb + r) * 4096 + gcol;
                const float sr = acc_r[m][nf][r] + br;
                const float sz = acc_z[m][nf][r] + bz;
                const float rg = 1.f / (1.f + __expf(-sr));
                const float zg = 1.f / (1.f + __expf(-sz));
                const float tin = (acc_nx[m][nf][r] + bnx) + rg * (acc_nh[m][nf][r] + bnh);
                const float e2 = __expf(-2.f * tin);
                const float ng = 2.f / (1.f + e2) - 1.f;
                const float hv = hst[idx];
                out[idx] = ng + zg * (hv - ng);
            }
        }
    }
}

extern "C" void kernel_launch(void* const* d_in, const int* in_sizes, int n_in,
                              void* d_out, int out_size, void* d_ws, size_t ws_size,
                              hipStream_t stream) {
    (void)in_sizes; (void)n_in; (void)out_size; (void)ws_size;
    const float* x    = (const float*)d_in[0];
    const float* h    = (const float*)d_in[1];
    const float* W_ih = (const float*)d_in[2];
    const float* W_hh = (const float*)d_in[3];
    const float* b_ih = (const float*)d_in[4];
    const float* b_hh = (const float*)d_in[5];
    short* Wcat = (short*)d_ws;               // 8*3*512*1024 bf16 = 24 MB

    wconv_kernel<<<6144, 256, 0, stream>>>(W_ih, W_hh, Wcat);
    gru_kernel<<<512, 512, 0, stream>>>(x, h, Wcat, b_ih, b_hh, (float*)d_out);
}